// Round 4
// baseline (344.933 us; speedup 1.0000x reference)
//
#include <hip/hip_runtime.h>
#include <math.h>

// Problem constants (from reference)
#define NN 100000          // nodes
#define LF 48              // features per node
#define NE 1600000         // edges
#define EDIMS 17           // edge_attr dim
#define MASKW 3125         // NN/32 bitmask words
#define CAP_E 16384        // per-level edge-list capacity (expected ~5k max level)
#define MAXLOC 12288       // active-node capacity (expected ~4.9k)
#define SCAN_TPB 256
#define SCAN_EPT 8         // edges per thread (two int4 loads)
#define SCAN_BLOCKS ((NE / SCAN_EPT + SCAN_TPB - 1) / SCAN_TPB)   // 782
#define ACT1_CAP 8192      // LDS list of M1-active locs (expected ~280)
#define ACT2_CAP 64        // LDS list of M2-active locs (expected ~17)

static_assert(NN == MASKW * 32, "mask width");
static_assert(NE % SCAN_EPT == 0, "8-edge scan");

__device__ __forceinline__ float gelu_f(float x) {
    // jax.nn.gelu(approximate=False) = x * 0.5 * (1 + erf(x/sqrt(2)))
    return 0.5f * x * (1.0f + erff(x * 0.7071067811865475f));
}
__device__ __forceinline__ float sigm_f(float x) {
    return 1.0f / (1.0f + expf(-x));
}
__device__ __forceinline__ float wave_sum(float v) {
    #pragma unroll
    for (int off = 32; off > 0; off >>= 1) v += __shfl_down(v, off, 64);
    return __shfl(v, 0, 64);   // broadcast lane-0 total
}

// Level-3 expand: S3 = {0} implicit (test dst==0, no mask at all). Folds zero-init
// of M1, M0 and both agg buffers (all consumed only by later dispatches).
__global__ void expand1_kernel(const int* __restrict__ src, const int* __restrict__ dst,
                               unsigned* __restrict__ M2, unsigned* __restrict__ M1,
                               unsigned* __restrict__ M0, float4* __restrict__ aggz,
                               int4* __restrict__ list0, int* __restrict__ counter)
{
    int tid = blockIdx.x * SCAN_TPB + threadIdx.x;
    int nthr = (int)gridDim.x * SCAN_TPB;
    for (int i = tid; i < MASKW; i += nthr) { M1[i] = 0u; M0[i] = 0u; }
    for (int i = tid; i < (2 * MAXLOC * LF) / 4; i += nthr)
        aggz[i] = make_float4(0.f, 0.f, 0.f, 0.f);
    if (tid == 0) atomicOr(&M2[0], 1u);   // S2 ⊇ S3 = {0}
    long e0 = (long)tid * SCAN_EPT;
    if (e0 < NE) {     // NE%8==0 -> whole 8-group in range
        int4 a = *(const int4*)(dst + e0);
        int4 b = *(const int4*)(dst + e0 + 4);
        int dv[8] = { a.x, a.y, a.z, a.w, b.x, b.y, b.z, b.w };
        #pragma unroll
        for (int k = 0; k < 8; ++k) {
            if (dv[k] == 0) {
                int e = (int)e0 + k;
                int s = src[e];
                int idx = atomicAdd(counter, 1);
                if (idx < CAP_E) list0[idx] = make_int4(s, 0, e, 0);
                atomicOr(&M2[s >> 5], 1u << (s & 31));
            }
        }
    }
}

// Level-2 expand with LDS-staged membership mask: M1 := M2 | src(edges with dst in M2).
__global__ void expand2_kernel(const int* __restrict__ src, const int* __restrict__ dst,
                               const unsigned* __restrict__ Min, unsigned* __restrict__ Mout,
                               int4* __restrict__ list, int* __restrict__ counter)
{
    __shared__ unsigned shM[MASKW];
    for (int i = threadIdx.x; i < MASKW; i += SCAN_TPB) shM[i] = Min[i];
    __syncthreads();
    if (blockIdx.x == 0) {        // sparse copy Min -> Mout (few nonzero words)
        for (int i = threadIdx.x; i < MASKW; i += SCAN_TPB) {
            unsigned m = shM[i];
            if (m) atomicOr(&Mout[i], m);
        }
    }
    int tid = blockIdx.x * SCAN_TPB + threadIdx.x;
    long e0 = (long)tid * SCAN_EPT;
    if (e0 < NE) {
        int4 a = *(const int4*)(dst + e0);
        int4 b = *(const int4*)(dst + e0 + 4);
        int dv[8] = { a.x, a.y, a.z, a.w, b.x, b.y, b.z, b.w };
        #pragma unroll
        for (int k = 0; k < 8; ++k) {
            int d = dv[k];
            if (shM[d >> 5] & (1u << (d & 31))) {
                int e = (int)e0 + k;
                int s = src[e];
                int idx = atomicAdd(counter, 1);
                if (idx < CAP_E) list[idx] = make_int4(s, d, e, 0);
                atomicOr(&Mout[s >> 5], 1u << (s & 31));
            }
        }
    }
}

// Level-1 expand with LDS mask AND inline loc assignment (no separate compact pass).
// M1-bit nodes assigned by block-0 word enumeration (unique); new src nodes assign
// exactly once via the atomicOr 0->1 transition on scratch M0, guarded by "not in M1".
__global__ void expand3_kernel(const int* __restrict__ src, const int* __restrict__ dst,
                               const unsigned* __restrict__ M1, unsigned* __restrict__ M0,
                               int4* __restrict__ list, int* __restrict__ counter,
                               int* __restrict__ n2l, int* __restrict__ l2n,
                               int* __restrict__ nloc)
{
    __shared__ unsigned shM[MASKW];
    for (int i = threadIdx.x; i < MASKW; i += SCAN_TPB) shM[i] = M1[i];
    __syncthreads();
    if (blockIdx.x == 0) {        // enumerate M1 nodes -> locs
        for (int w = threadIdx.x; w < MASKW; w += SCAN_TPB) {
            unsigned bits = shM[w];
            while (bits) {
                int bpos = __ffs(bits) - 1;
                bits &= bits - 1;
                int node = w * 32 + bpos;
                int loc = atomicAdd(nloc, 1);
                if (loc < MAXLOC) { n2l[node] = loc; l2n[loc] = node; }
            }
        }
    }
    int tid = blockIdx.x * SCAN_TPB + threadIdx.x;
    long e0 = (long)tid * SCAN_EPT;
    if (e0 < NE) {
        int4 a = *(const int4*)(dst + e0);
        int4 b = *(const int4*)(dst + e0 + 4);
        int dv[8] = { a.x, a.y, a.z, a.w, b.x, b.y, b.z, b.w };
        #pragma unroll
        for (int k = 0; k < 8; ++k) {
            int d = dv[k];
            if (shM[d >> 5] & (1u << (d & 31))) {
                int e = (int)e0 + k;
                int s = src[e];
                int idx = atomicAdd(counter, 1);
                if (idx < CAP_E) list[idx] = make_int4(s, d, e, 0);
                unsigned sb = 1u << (s & 31);
                unsigned old = atomicOr(&M0[s >> 5], sb);
                if (!(old & sb) && !(shM[s >> 5] & sb)) {
                    int loc = atomicAdd(nloc, 1);
                    if (loc < MAXLOC) { n2l[s] = loc; l2n[loc] = s; }
                }
            }
        }
    }
}

// Per-edge loop-invariant MLP scalar, wave-cooperative (64 lanes, no LDS/syncthreads):
//   w0 = gelu(relu(gelu(ea@W1+b1)@W2+b2)@Wg+bg)@Ww + bw    (broadcast to all lanes)
__device__ float w0_compute(long e, const float* __restrict__ ea_g,
                            const float* __restrict__ W1, const float* __restrict__ b1,
                            const float* __restrict__ W2, const float* __restrict__ b2,
                            const float* __restrict__ Wg, const float* __restrict__ bg,
                            const float* __restrict__ Ww, const float* __restrict__ bw,
                            int lane)
{
    float ea = 0.f;
    if (lane < EDIMS) ea = ea_g[e * EDIMS + lane];
    float h1 = 0.f;
    if (lane < 48) {
        float acc = b1[lane];
        #pragma unroll
        for (int k = 0; k < EDIMS; ++k) acc += __shfl(ea, k, 64) * W1[k * 48 + lane];
        h1 = gelu_f(acc);
    }
    float h2 = 0.f;
    if (lane < 48) {
        float acc = b2[lane];
        #pragma unroll 8
        for (int k = 0; k < 48; ++k) acc += __shfl(h1, k, 64) * W2[k * 48 + lane];
        h2 = fmaxf(acc, 0.f);
    }
    float part = 0.f;
    if (lane < 48) {
        float acc = bg[lane];
        #pragma unroll 8
        for (int k = 0; k < 48; ++k) acc += __shfl(h2, k, 64) * Wg[k * 48 + lane];
        part = gelu_f(acc) * Ww[lane];
    }
    return wave_sum(part) + bw[0];
}

// Fused: (a) init X0/VA for M1-active locs only (~280 nodes; all later reads are M1-local);
// (b) per-edge w0 for all 3 lists; E1 edges additionally do the iter-1 aggregation
// directly from RAW inputs (x0[src]=nodes*valid, mv0[src]=mean(valid)).
__global__ void fused_kernel(const int* __restrict__ counters, const int* __restrict__ l2n,
                             const int* __restrict__ n2l, const unsigned* __restrict__ M1,
                             const float* __restrict__ nodes, const float* __restrict__ valid,
                             float* __restrict__ X0, float* __restrict__ VA,
                             int4* __restrict__ lists, const float* __restrict__ ea_g,
                             const float* __restrict__ W1, const float* __restrict__ b1,
                             const float* __restrict__ W2, const float* __restrict__ b2,
                             const float* __restrict__ Wg, const float* __restrict__ bg,
                             const float* __restrict__ Ww, const float* __restrict__ bw,
                             float* __restrict__ agg0)
{
    int tid = blockIdx.x * 256 + threadIdx.x;
    int nthr = (int)gridDim.x * 256;
    int nl = counters[3]; if (nl > MAXLOC) nl = MAXLOC;
    for (int loc = tid; loc < nl; loc += nthr) {
        int node = l2n[loc];
        if (!(M1[node >> 5] & (1u << (node & 31)))) continue;
        const float4* nv = (const float4*)(valid + (size_t)node * LF);
        const float4* nx = (const float4*)(nodes + (size_t)node * LF);
        float4* X0v = (float4*)(X0 + (size_t)loc * LF);
        float4* V0v = (float4*)(VA + (size_t)loc * LF);
        #pragma unroll
        for (int k = 0; k < 12; ++k) {
            float4 v = nv[k], x = nx[k];
            x.x *= v.x; x.y *= v.y; x.z *= v.z; x.w *= v.w;
            X0v[k] = x; V0v[k] = v;
        }
    }
    int c0 = counters[0]; c0 = (c0 > CAP_E) ? CAP_E : c0;
    int c1 = counters[1]; c1 = (c1 > CAP_E) ? CAP_E : c1;
    int c2 = counters[2]; c2 = (c2 > CAP_E) ? CAP_E : c2;
    int total = c0 + c1 + c2;
    int lane = tid & 63;
    for (int g = tid >> 6; g < total; g += (nthr >> 6)) {
        int4* entp;
        bool isE1 = false;
        if (g < c0)           entp = lists + g;
        else if (g < c0 + c1) entp = lists + CAP_E + (g - c0);
        else                { entp = lists + 2 * CAP_E + (g - c0 - c1); isE1 = true; }
        int4 ent = *entp;
        float w0 = w0_compute((long)ent.z, ea_g, W1, b1, W2, b2, Wg, bg, Ww, bw, lane);
        if (isE1) {
            int s = ent.x;                          // global node id
            int dl = n2l[ent.y]; if ((unsigned)dl >= MAXLOC) dl = 0;
            float v = 0.f, x = 0.f;
            if (lane < 48) {
                v = valid[(size_t)s * LF + lane];
                x = nodes[(size_t)s * LF + lane] * v;
            }
            float mv = wave_sum(v) * (1.0f / 48.0f);
            float sg = sigm_f(mv * w0);
            if (lane < 48) atomicAdd(&agg0[dl * LF + lane], sg * x);
        } else if (lane == 0) {
            int sl = n2l[ent.x]; if ((unsigned)sl >= MAXLOC) sl = 0;
            int dl = n2l[ent.y]; if ((unsigned)dl >= MAXLOC) dl = 0;
            *entp = make_int4(sl, dl, ent.z, __float_as_int(w0));
        }
    }
}

// ---- single-block tail: upd1 -> agg2 -> upd2 -> agg3 -> upd3 -> out ----
// Wave-per-node (lane = feature) for coalesced 192B rows; active lists compacted to
// LDS up-front; agg3 (dst = node 0 only) accumulated in LDS.
__global__ void __launch_bounds__(1024) tail_kernel(
    const int* __restrict__ counters, const int* __restrict__ l2n, const int* __restrict__ n2l,
    const unsigned* __restrict__ M1, const unsigned* __restrict__ M2,
    const int4* __restrict__ lists, const float* __restrict__ X0,
    float* __restrict__ XA, float* __restrict__ XB,
    float* __restrict__ VA, float* __restrict__ VB,
    float* __restrict__ MVA, float* __restrict__ MVB,
    const float* __restrict__ agg0, float* __restrict__ agg1b,
    const float* __restrict__ Wf, const float* __restrict__ bf, float* __restrict__ out)
{
    __shared__ int act1[ACT1_CAP];
    __shared__ int act2[ACT2_CAP];
    __shared__ int cnts[2];
    __shared__ float agg3s[LF];
    int tid = threadIdx.x;
    if (tid < 2) cnts[tid] = 0;
    if (tid < LF) agg3s[tid] = 0.f;
    __syncthreads();

    int nl = counters[3]; if (nl > MAXLOC) nl = MAXLOC;
    for (int loc = tid; loc < nl; loc += 1024) {
        int node = l2n[loc];
        unsigned bit = 1u << (node & 31);
        unsigned w1 = M1[node >> 5], w2 = M2[node >> 5];
        if (w1 & bit) { int i = atomicAdd(&cnts[0], 1); if (i < ACT1_CAP) act1[i] = loc; }
        if (w2 & bit) { int i = atomicAdd(&cnts[1], 1); if (i < ACT2_CAP) act2[i] = loc; }
    }
    __syncthreads();
    int c1n = cnts[0]; if (c1n > ACT1_CAP) c1n = ACT1_CAP;
    int c2n = cnts[1]; if (c2n > ACT2_CAP) c2n = ACT2_CAP;
    int wave = tid >> 6, lane = tid & 63;
    float wf0 = Wf[0], wf1 = Wf[1], wf2 = Wf[2], bfs = bf[0];

    // iter-1 update: nodes in M1; X0/VA -> XA/VB/MVB  (Xp == Xorig == X0 here)
    for (int i = wave; i < c1n; i += 16) {
        int loc = act1[i];
        float nh = 0.f, xo = 0.f, vp = 0.f;
        if (lane < 48) {
            nh = agg0[loc * LF + lane];
            xo = X0[loc * LF + lane];
            vp = VA[loc * LF + lane];
        }
        float nv = 1.0f - vp;
        float m = sigm_f(nh * wf0 + xo * wf1 + nv * wf2 + bfs);
        float xn = (1.0f - m) * xo + nv * m * nh;
        float vn = ((xo != xn) || (vp > 0.f)) ? 1.0f : 0.0f;
        if (lane == 0) vn = 0.0f;
        if (lane < 48) { XA[loc * LF + lane] = xn; VB[loc * LF + lane] = vn; }
        float s = (lane < 48) ? vn : 0.f;
        #pragma unroll
        for (int off = 32; off > 0; off >>= 1) s += __shfl_down(s, off, 64);
        if (lane == 0) MVB[loc] = s * (1.0f / 48.0f);
    }
    __syncthreads();

    // iter-2 aggregation: E2 (slot1), wave-per-edge -> agg1b (global atomics, ~270 edges)
    int cE2 = counters[1]; if (cE2 > CAP_E) cE2 = CAP_E;
    for (int i = wave; i < cE2; i += 16) {
        int4 ent = lists[CAP_E + i];
        if ((unsigned)ent.x >= MAXLOC || (unsigned)ent.y >= MAXLOC) continue;
        float sg = sigm_f(MVB[ent.x] * __int_as_float(ent.w));
        if (lane < 48) atomicAdd(&agg1b[ent.y * LF + lane], sg * XA[ent.x * LF + lane]);
    }
    __syncthreads();

    // iter-2 update: nodes in M2; XA/VB -> XB/VA/MVA  (Xorig = X0)
    for (int i = wave; i < c2n; i += 16) {
        int loc = act2[i];
        float nh = 0.f, xo = 0.f, vp = 0.f, xorig = 0.f;
        if (lane < 48) {
            nh = agg1b[loc * LF + lane];
            xo = XA[loc * LF + lane];
            vp = VB[loc * LF + lane];
            xorig = X0[loc * LF + lane];
        }
        float nv = 1.0f - vp;
        float m = sigm_f(nh * wf0 + xo * wf1 + nv * wf2 + bfs);
        float xn = (1.0f - m) * xo + nv * m * nh;
        float vn = ((xorig != xn) || (vp > 0.f)) ? 1.0f : 0.0f;
        if (lane == 0) vn = 0.0f;
        if (lane < 48) { XB[loc * LF + lane] = xn; VA[loc * LF + lane] = vn; }
        float s = (lane < 48) ? vn : 0.f;
        #pragma unroll
        for (int off = 32; off > 0; off >>= 1) s += __shfl_down(s, off, 64);
        if (lane == 0) MVA[loc] = s * (1.0f / 48.0f);
    }
    __syncthreads();

    // iter-3 aggregation: E3 (slot0), dst = node 0 only -> LDS accumulator
    int cE3 = counters[0]; if (cE3 > CAP_E) cE3 = CAP_E;
    for (int i = wave; i < cE3; i += 16) {
        int4 ent = lists[i];
        if ((unsigned)ent.x >= MAXLOC) continue;
        float sg = sigm_f(MVA[ent.x] * __int_as_float(ent.w));
        if (lane < 48) atomicAdd(&agg3s[lane], sg * XB[ent.x * LF + lane]);
    }
    __syncthreads();

    // iter-3 update for node 0 -> output row
    if (tid < 48) {
        int loc0 = n2l[0]; if ((unsigned)loc0 >= MAXLOC) loc0 = 0;
        float nh = agg3s[tid];
        float xo = XB[loc0 * LF + tid];
        float vp = VA[loc0 * LF + tid];
        float nv = 1.0f - vp;
        float m = sigm_f(nh * wf0 + xo * wf1 + nv * wf2 + bfs);
        out[tid] = (1.0f - m) * xo + nv * m * nh;
    }
}

extern "C" void kernel_launch(void* const* d_in, const int* in_sizes, int n_in,
                              void* d_out, int out_size, void* d_ws, size_t ws_size,
                              hipStream_t stream)
{
    (void)in_sizes; (void)n_in; (void)out_size;
    const float* nodes = (const float*)d_in[0];
    const int*   eidx  = (const int*)d_in[1];     // (2,E) int32
    const float* eattr = (const float*)d_in[2];
    const float* valid = (const float*)d_in[3];
    // d_in[4]=r, d_in[5]=fx unused by reference
    const float* W1 = (const float*)d_in[6];
    const float* b1 = (const float*)d_in[7];
    const float* W2 = (const float*)d_in[8];
    const float* b2 = (const float*)d_in[9];
    const float* Wg = (const float*)d_in[10];
    const float* bg = (const float*)d_in[11];
    const float* Ww = (const float*)d_in[12];
    const float* bw = (const float*)d_in[13];
    const float* Wf = (const float*)d_in[14];
    const float* bf = (const float*)d_in[15];
    const int* src = eidx;
    const int* dst = eidx + NE;

    char* ws = (char*)d_ws;
    size_t off = 0;
    auto alloc = [&](size_t bytes) -> char* {
        char* p = ws + off;
        off += (bytes + 255) & ~(size_t)255;
        return p;
    };
    // counters + M2 contiguous -> single hipMemsetAsync covers both
    char*     zb = alloc(256 + MASKW * 4);
    int*      counters = (int*)zb;                // [0]=|E3| [1]=|E2| [2]=|E1| [3]=nloc
    unsigned* M2 = (unsigned*)(zb + 256);
    unsigned* M1 = (unsigned*)alloc(MASKW * 4);
    unsigned* M0 = (unsigned*)alloc(MASKW * 4);   // scratch dedup mask for expand3
    int*      n2l = (int*)alloc((size_t)NN * 4);
    int*      l2n = (int*)alloc((size_t)MAXLOC * 4);
    int4*     lists = (int4*)alloc((size_t)3 * CAP_E * 16); // slot0=E3, slot1=E2, slot2=E1
    float*    X0 = (float*)alloc((size_t)MAXLOC * LF * 4);
    float*    XA = (float*)alloc((size_t)MAXLOC * LF * 4);
    float*    XB = (float*)alloc((size_t)MAXLOC * LF * 4);
    float*    VA = (float*)alloc((size_t)MAXLOC * LF * 4);
    float*    VB = (float*)alloc((size_t)MAXLOC * LF * 4);
    float*    MVA = (float*)alloc((size_t)MAXLOC * 4);
    float*    MVB = (float*)alloc((size_t)MAXLOC * 4);
    float*    agg = (float*)alloc((size_t)2 * MAXLOC * LF * 4); // agg0 | agg1b
    if (off > ws_size) return;   // ~18 MB needed; fail loudly rather than corrupt
    float* agg0  = agg;
    float* agg1b = agg + MAXLOC * LF;

    hipMemsetAsync(zb, 0, 256 + MASKW * 4, stream);

    // Backward BFS (3 levels); zero-init folded into expand1; loc-assign folded into
    // expand3; membership masks staged in LDS to kill per-edge L1 gathers.
    expand1_kernel<<<SCAN_BLOCKS, SCAN_TPB, 0, stream>>>(src, dst, M2, M1, M0, (float4*)agg,
                                                         lists + 0 * CAP_E, counters + 0);
    expand2_kernel<<<SCAN_BLOCKS, SCAN_TPB, 0, stream>>>(src, dst, M2, M1,
                                                         lists + 1 * CAP_E, counters + 1);
    expand3_kernel<<<SCAN_BLOCKS, SCAN_TPB, 0, stream>>>(src, dst, M1, M0,
                                                         lists + 2 * CAP_E, counters + 2,
                                                         n2l, l2n, counters + 3);
    fused_kernel<<<1024, 256, 0, stream>>>(counters, l2n, n2l, M1, nodes, valid,
                                           X0, VA, lists, eattr,
                                           W1, b1, W2, b2, Wg, bg, Ww, bw, agg0);
    tail_kernel<<<1, 1024, 0, stream>>>(counters, l2n, n2l, M1, M2, lists, X0,
                                        XA, XB, VA, VB, MVA, MVB,
                                        agg0, agg1b, Wf, bf, (float*)d_out);
}